// Round 2
// baseline (242.181 us; speedup 1.0000x reference)
//
#include <hip/hip_runtime.h>
#include <hip/hip_cooperative_groups.h>
#include <math.h>

namespace cg = cooperative_groups;

#define N_POINTS 16384
#define CELLS_PER_CLOUD 4096        // 16^3 per cloud, cell edge = r = 1/16
#define N_CELLS 32768               // 8 clouds
#define CAP 16                      // bucket capacity; lambda~0.5/cell, P(>16)~1e-12
#define NBR_STRIDE 32               // max neighbor count (established: cnt<=32)
#define TPB 512                     // 64 points x 8 cell-groups/channels
#define NBLK (N_POINTS / 64)        // 256 blocks -> 1 block/CU, co-resident

constexpr double R2D = 1.0 / 256.0; // (1/16)^2, exact in binary

// ---------------------------------------------------------------------------
// Single cooperative kernel, 5 phases separated by grid.sync():
//   P0: zero cnt + output pos/batch copies
//   P1: pos4 pack + cell-bucket build (atomics)
//   P2: 27-cell radius search (8 threads/point) + layer a (6->8->8)
//   P3: conv b (8->16->16) over LDS-resident neighbor lists
//   P4: conv c (16->32->32) -> final output
// Block owns 64 points; s_hits persists in LDS across syncs (block resident
// under cooperative launch), so the global nbr array is eliminated.
// Max-agg is exactly commutative -> hit order nondeterminism changes no bit.
// ---------------------------------------------------------------------------
__global__ __launch_bounds__(TPB) void k_mega(
    const float* __restrict__ pos, const int* __restrict__ batch,
    const float* __restrict__ W1a, const float* __restrict__ b1a,
    const float* __restrict__ W2a, const float* __restrict__ b2a,
    const float* __restrict__ W1b, const float* __restrict__ b1b,
    const float* __restrict__ W2b, const float* __restrict__ b2b,
    const float* __restrict__ W1c, const float* __restrict__ b1c,
    const float* __restrict__ W2c, const float* __restrict__ b2c,
    float* __restrict__ out, int* __restrict__ cnt,
    float4* __restrict__ bucket, float4* __restrict__ pos4,
    float* __restrict__ out_a, float* __restrict__ out_b)
{
    cg::grid_group grid = cg::this_grid();

    __shared__ float sW1a[48], sB1a[8], sW2a[64], sB2a[8];
    __shared__ float sW1b[11 * 16], sB1b[16], sW2b[16 * 16], sB2b[16];
    __shared__ float sW1c[19 * 32], sB1c[32], sW2c[32 * 32], sB2c[32];
    __shared__ float4 s_hits[NBR_STRIDE][64];   // [slot][point] : 32 KB
    __shared__ int   s_k[64];
    __shared__ float s_mx[64][9];               // +1 pad vs 8 (bank spread)
    __shared__ float s_aggb[64][17];            // +1 pad
    __shared__ float s_aggc[64][33];            // +1 pad

    int t = threadIdx.x, b = blockIdx.x;
    int p = t & 63;          // point-in-block
    int g = t >> 6;          // cell-group / channel-group 0..7 (wave id)

    // ---- weight staging into LDS (consumed only after syncs) ----
    if (t < 48) sW1a[t] = W1a[t];
    if (t < 8)  { sB1a[t] = b1a[t]; sB2a[t] = b2a[t]; }
    if (t < 64) { sW2a[t] = W2a[t]; s_k[t] = 0; }
    if (t < 176) sW1b[t] = W1b[t];
    if (t < 256) sW2b[t] = W2b[t];
    if (t < 16) { sB1b[t] = b1b[t]; sB2b[t] = b2b[t]; }
    for (int k = t; k < 608;  k += TPB) sW1c[k] = W1c[k];
    for (int k = t; k < 1024; k += TPB) sW2c[k] = W2c[k];
    if (t < 32) { sB1c[t] = b1c[t]; sB2c[t] = b2c[t]; }

    // ================= P0: zero cnt + output copies =================
    if (t < 128) cnt[b * 128 + t] = 0;                     // 256*128 = 32768
    if (t < 192) { int idx = b * 192 + t; out[idx] = pos[idx]; }   // 3N pos copy
    if (t < 64) {
        int i = b * 64 + t;
        out[3 * N_POINTS + 32 * N_POINTS + i] = (float)batch[i];
    }
    grid.sync();

    // ================= P1: pos4 pack + bucket build =================
    if (t < 64) {
        int i = b * 64 + t;
        float x = pos[3 * i], y = pos[3 * i + 1], z = pos[3 * i + 2];
        int ix = min(max((int)(x * 16.f), 0), 15);
        int iy = min(max((int)(y * 16.f), 0), 15);
        int iz = min(max((int)(z * 16.f), 0), 15);
        int cell = ((batch[i] * 16 + iz) * 16 + iy) * 16 + ix;
        pos4[i] = make_float4(x, y, z, __int_as_float(cell));
        int slot = atomicAdd(&cnt[cell], 1);
        if (slot < CAP) bucket[cell * CAP + slot] = make_float4(x, y, z, __int_as_float(i));
    }
    grid.sync();

    // ================= P2: search + layer a =================
    int i = b * 64 + p;
    float4 pi4 = pos4[i];
    float xi = pi4.x, yi = pi4.y, zi = pi4.z;
    double xd = (double)xi, yd = (double)yi, zd = (double)zi;
    int cell0 = __float_as_int(pi4.w);
    int ix = cell0 & 15, iy = (cell0 >> 4) & 15, iz = (cell0 >> 8) & 15;
    int cb = cell0 & ~(CELLS_PER_CLOUD - 1);

    int n[4], cid[4];
#pragma unroll
    for (int cc = 0; cc < 4; cc++) {
        int c = g + 8 * cc;                       // 0..31; >=27 masked off
        int dz = c / 9 - 1, dy = (c / 3) % 3 - 1, dx = c % 3 - 1;
        int zz = iz + dz, yy = iy + dy, xx = ix + dx;
        bool ok = (c < 27) & ((zz | yy | xx) >= 0) & (zz < 16) & (yy < 16) & (xx < 16);
        int zc = min(max(zz, 0), 15), yc = min(max(yy, 0), 15),
            xc = min(max(xx, 0), 15);
        cid[cc] = cb + (zc << 8) + (yc << 4) + xc;   // always a valid address
        int nc = min(cnt[cid[cc]], CAP);             // unconditional load
        n[cc] = ok ? nc : 0;
    }
    int nmax = 0;
#pragma unroll
    for (int cc = 0; cc < 4; cc++) nmax = max(nmax, n[cc]);

    for (int s = 0; s < nmax; s++) {
#pragma unroll
        for (int cc = 0; cc < 4; cc++) {
            if (s < n[cc]) {
                float4 q = bucket[cid[cc] * CAP + s];
                double ddx = xd - (double)q.x, ddy = yd - (double)q.y,
                       ddz = zd - (double)q.z;
                double d2 = ddx * ddx + ddy * ddy + ddz * ddz;
                if (d2 <= R2D) {
                    int slot = atomicAdd(&s_k[p], 1);
                    if (slot < NBR_STRIDE) s_hits[slot][p] = q;
                }
            }
        }
    }
    __syncthreads();
    int kc = min(s_k[p], NBR_STRIDE);               // same for all 8 g-threads of p

    // layer a, channel m = g (8 channels across 8 waves)
    {
        float mxv = 0.f;                            // self always valid, relu >= 0
        for (int kk = 0; kk < kc; kk++) {
            float4 q = s_hits[kk][p];
            float in6[6] = { q.x, q.y, q.z, q.x - xi, q.y - yi, q.z - zi };
            float h = sB1a[g];
#pragma unroll
            for (int c6 = 0; c6 < 6; c6++) h = fmaf(in6[c6], sW1a[c6 * 8 + g], h);
            mxv = fmaxf(mxv, fmaxf(h, 0.f));
        }
        s_mx[p][g] = mxv;
    }
    __syncthreads();
    {
        float o = sB2a[g];
#pragma unroll
        for (int k = 0; k < 8; k++) o = fmaf(s_mx[p][k], sW2a[k * 8 + g], o);
        out_a[i * 8 + g] = o > 0.f ? o : expm1f(o);   // celu, alpha=1
    }
    grid.sync();

    // ================= P3: conv b (8 -> 16 -> 16) =================
    {
        const float4* xa = (const float4*)out_a;
        int m0 = g, m1 = g + 8;
        float w0[11], w1[11];
#pragma unroll
        for (int k = 0; k < 11; k++) { w0[k] = sW1b[k * 16 + m0]; w1[k] = sW1b[k * 16 + m1]; }
        float bb0 = sB1b[m0], bb1 = sB1b[m1];
        float mx0 = 0.f, mx1 = 0.f;
        for (int kk = 0; kk < kc; kk++) {
            float4 q = s_hits[kk][p];
            int j = __float_as_int(q.w);
            float4 v0 = xa[j * 2], v1 = xa[j * 2 + 1];
            float rx = q.x - xi, ry = q.y - yi, rz = q.z - zi;
            float h0 = bb0, h1 = bb1;
            h0 = fmaf(v0.x, w0[0], h0); h1 = fmaf(v0.x, w1[0], h1);
            h0 = fmaf(v0.y, w0[1], h0); h1 = fmaf(v0.y, w1[1], h1);
            h0 = fmaf(v0.z, w0[2], h0); h1 = fmaf(v0.z, w1[2], h1);
            h0 = fmaf(v0.w, w0[3], h0); h1 = fmaf(v0.w, w1[3], h1);
            h0 = fmaf(v1.x, w0[4], h0); h1 = fmaf(v1.x, w1[4], h1);
            h0 = fmaf(v1.y, w0[5], h0); h1 = fmaf(v1.y, w1[5], h1);
            h0 = fmaf(v1.z, w0[6], h0); h1 = fmaf(v1.z, w1[6], h1);
            h0 = fmaf(v1.w, w0[7], h0); h1 = fmaf(v1.w, w1[7], h1);
            h0 = fmaf(rx, w0[8],  h0);  h1 = fmaf(rx, w1[8],  h1);
            h0 = fmaf(ry, w0[9],  h0);  h1 = fmaf(ry, w1[9],  h1);
            h0 = fmaf(rz, w0[10], h0);  h1 = fmaf(rz, w1[10], h1);
            mx0 = fmaxf(mx0, fmaxf(h0, 0.f));
            mx1 = fmaxf(mx1, fmaxf(h1, 0.f));
        }
        s_aggb[p][m0] = mx0;
        s_aggb[p][m1] = mx1;
        __syncthreads();
        float o0 = sB2b[m0], o1 = sB2b[m1];
#pragma unroll
        for (int k = 0; k < 16; k++) {
            float a = s_aggb[p][k];
            o0 = fmaf(a, sW2b[k * 16 + m0], o0);
            o1 = fmaf(a, sW2b[k * 16 + m1], o1);
        }
        out_b[i * 16 + m0] = o0 > 0.f ? o0 : expm1f(o0);
        out_b[i * 16 + m1] = o1 > 0.f ? o1 : expm1f(o1);
    }
    grid.sync();

    // ================= P4: conv c (16 -> 32 -> 32) -> final out =================
    {
        const float4* xb = (const float4*)out_b;
        float w1[4][19];
#pragma unroll
        for (int cc = 0; cc < 4; cc++) {
            int mm = g + 8 * cc;
#pragma unroll
            for (int k = 0; k < 19; k++) w1[cc][k] = sW1c[k * 32 + mm];
        }
        float mx[4] = {0.f, 0.f, 0.f, 0.f};
        for (int kk = 0; kk < kc; kk++) {
            float4 q = s_hits[kk][p];
            int j = __float_as_int(q.w);
            float4 v0 = xb[j * 4], v1 = xb[j * 4 + 1],
                   v2 = xb[j * 4 + 2], v3 = xb[j * 4 + 3];
            float rx = q.x - xi, ry = q.y - yi, rz = q.z - zi;
#pragma unroll
            for (int cc = 0; cc < 4; cc++) {
                float h = sB1c[g + 8 * cc];
                h = fmaf(v0.x, w1[cc][0],  h);
                h = fmaf(v0.y, w1[cc][1],  h);
                h = fmaf(v0.z, w1[cc][2],  h);
                h = fmaf(v0.w, w1[cc][3],  h);
                h = fmaf(v1.x, w1[cc][4],  h);
                h = fmaf(v1.y, w1[cc][5],  h);
                h = fmaf(v1.z, w1[cc][6],  h);
                h = fmaf(v1.w, w1[cc][7],  h);
                h = fmaf(v2.x, w1[cc][8],  h);
                h = fmaf(v2.y, w1[cc][9],  h);
                h = fmaf(v2.z, w1[cc][10], h);
                h = fmaf(v2.w, w1[cc][11], h);
                h = fmaf(v3.x, w1[cc][12], h);
                h = fmaf(v3.y, w1[cc][13], h);
                h = fmaf(v3.z, w1[cc][14], h);
                h = fmaf(v3.w, w1[cc][15], h);
                h = fmaf(rx, w1[cc][16], h);
                h = fmaf(ry, w1[cc][17], h);
                h = fmaf(rz, w1[cc][18], h);
                mx[cc] = fmaxf(mx[cc], fmaxf(h, 0.f));
            }
        }
#pragma unroll
        for (int cc = 0; cc < 4; cc++) s_aggc[p][g + 8 * cc] = mx[cc];
        __syncthreads();
        float o[4];
#pragma unroll
        for (int cc = 0; cc < 4; cc++) o[cc] = sB2c[g + 8 * cc];
#pragma unroll
        for (int k = 0; k < 32; k++) {
            float a = s_aggc[p][k];
#pragma unroll
            for (int cc = 0; cc < 4; cc++)
                o[cc] = fmaf(a, sW2c[k * 32 + g + 8 * cc], o[cc]);
        }
#pragma unroll
        for (int cc = 0; cc < 4; cc++) {
            float v = o[cc];
            out[3 * N_POINTS + i * 32 + g + 8 * cc] = v > 0.f ? v : expm1f(v);
        }
    }
}

// ---------------------------------------------------------------------------
extern "C" void kernel_launch(void* const* d_in, const int* in_sizes, int n_in,
                              void* d_out, int out_size, void* d_ws, size_t ws_size,
                              hipStream_t stream)
{
    const float* pos   = (const float*)d_in[0];
    // d_in[1] = rgb: unused by reference
    const int*   batch = (const int*)d_in[2];
    const float* W1a = (const float*)d_in[3];
    const float* b1a = (const float*)d_in[4];
    const float* W2a = (const float*)d_in[5];
    const float* b2a = (const float*)d_in[6];
    const float* W1b = (const float*)d_in[7];
    const float* b1b = (const float*)d_in[8];
    const float* W2b = (const float*)d_in[9];
    const float* b2b = (const float*)d_in[10];
    const float* W1c = (const float*)d_in[11];
    const float* b1c = (const float*)d_in[12];
    const float* W2c = (const float*)d_in[13];
    const float* b2c = (const float*)d_in[14];

    float* out = (float*)d_out;

    char* ws = (char*)d_ws;
    size_t off = 0;
    auto alloc = [&](size_t bytes) {
        char* p = ws + off; off += (bytes + 255) & ~size_t(255); return p;
    };
    int*    cnt     = (int*)alloc(N_CELLS * 4);
    float4* bucket  = (float4*)alloc((size_t)N_CELLS * CAP * 16);
    float4* pos4    = (float4*)alloc(N_POINTS * 16);
    float*  out_a   = (float*)alloc(N_POINTS * 8 * 4);
    float*  out_b   = (float*)alloc(N_POINTS * 16 * 4);

    void* args[] = { (void*)&pos, (void*)&batch,
                     (void*)&W1a, (void*)&b1a, (void*)&W2a, (void*)&b2a,
                     (void*)&W1b, (void*)&b1b, (void*)&W2b, (void*)&b2b,
                     (void*)&W1c, (void*)&b1c, (void*)&W2c, (void*)&b2c,
                     (void*)&out, (void*)&cnt, (void*)&bucket, (void*)&pos4,
                     (void*)&out_a, (void*)&out_b };
    hipLaunchCooperativeKernel((const void*)k_mega, dim3(NBLK), dim3(TPB),
                               args, 0, stream);
}

// Round 3
// 112.526 us; speedup vs baseline: 2.1522x; 2.1522x over previous
//
#include <hip/hip_runtime.h>
#include <math.h>

#define N_POINTS 16384
#define CELLS_PER_CLOUD 4096        // 16^3 per cloud, cell edge = r = 1/16
#define N_CELLS 32768               // 8 clouds
#define CAP 16                      // bucket capacity; lambda~0.5/cell, P(>16)~1e-12
#define NBR_STRIDE 32               // max neighbor count (established: cnt<=32)

constexpr double R2D = 1.0 / 256.0; // (1/16)^2, exact in binary

// ---------------------------------------------------------------------------
// K1: output copies (pos, batch->float) + cell-bucket build + pos4 pack.
// 64 blocks x 256 = N_POINTS threads.
// ---------------------------------------------------------------------------
__global__ __launch_bounds__(256) void k_prep(const float* __restrict__ pos,
                                              const int* __restrict__ batch,
                                              float* __restrict__ out,
                                              int* __restrict__ cnt,
                                              float4* __restrict__ bucket,
                                              float4* __restrict__ pos4)
{
    int i = blockIdx.x * 256 + threadIdx.x;
    out[i]                = pos[i];                      // output 0: pos copy [N,3]
    out[i + N_POINTS]     = pos[i + N_POINTS];
    out[i + 2 * N_POINTS] = pos[i + 2 * N_POINTS];
    out[3 * N_POINTS + 32 * N_POINTS + i] = (float)batch[i];   // output 2

    float x = pos[3 * i], y = pos[3 * i + 1], z = pos[3 * i + 2];
    int ix = min(max((int)(x * 16.f), 0), 15);
    int iy = min(max((int)(y * 16.f), 0), 15);
    int iz = min(max((int)(z * 16.f), 0), 15);
    int cell = ((batch[i] * 16 + iz) * 16 + iy) * 16 + ix;
    pos4[i] = make_float4(x, y, z, __int_as_float(cell));
    int slot = atomicAdd(&cnt[cell], 1);
    if (slot < CAP) bucket[cell * CAP + slot] = make_float4(x, y, z, __int_as_float(i));
}

// ---------------------------------------------------------------------------
// K2: 27-cell radius search (fp64 test) fused with layer a (6->8->8).
// 8 threads per point (cells interleaved c = g + 8*cc), block = 512 threads
// = 64 points x 8 cell-groups -> 8 waves/CU. Hits compact through an LDS
// atomic slot counter; max-agg commutative -> order nondeterminism is benign.
// (unchanged from the 117 us version)
// ---------------------------------------------------------------------------
__global__ __launch_bounds__(512) void k_search_a(
    const float4* __restrict__ pos4,
    const int* __restrict__ cnt, const float4* __restrict__ bucket,
    const float* __restrict__ W1, const float* __restrict__ b1,
    const float* __restrict__ W2, const float* __restrict__ b2,
    float* __restrict__ out_a, float4* __restrict__ nbr, int* __restrict__ nbr_cnt)
{
    __shared__ float sW1[48], sB1[8], sW2[64], sB2[8];
    __shared__ float4 s_hits[NBR_STRIDE][64];   // [slot][point] : 32 KB
    __shared__ int s_k[64];

    int t = threadIdx.x;
    int p = t & 63;          // point-in-block
    int g = t >> 6;          // cell-group 0..7 (wave id)

    if (t < 48) sW1[t] = W1[t];
    if (t < 8) { sB1[t] = b1[t]; sB2[t] = b2[t]; }
    if (t < 64) { sW2[t] = W2[t]; s_k[t] = 0; }
    __syncthreads();

    int i = blockIdx.x * 64 + p;
    float4 pi4 = pos4[i];
    float xi = pi4.x, yi = pi4.y, zi = pi4.z;
    double xd = (double)xi, yd = (double)yi, zd = (double)zi;
    int cell0 = __float_as_int(pi4.w);
    int ix = cell0 & 15, iy = (cell0 >> 4) & 15, iz = (cell0 >> 8) & 15;
    int cb = cell0 & ~(CELLS_PER_CLOUD - 1);

    int n[4], cid[4];
#pragma unroll
    for (int cc = 0; cc < 4; cc++) {
        int c = g + 8 * cc;                       // 0..31; >=27 masked off
        int dz = c / 9 - 1, dy = (c / 3) % 3 - 1, dx = c % 3 - 1;
        int zz = iz + dz, yy = iy + dy, xx = ix + dx;
        bool ok = (c < 27) & ((zz | yy | xx) >= 0) & (zz < 16) & (yy < 16) & (xx < 16);
        int zc = min(max(zz, 0), 15), yc = min(max(yy, 0), 15),
            xc = min(max(xx, 0), 15);
        cid[cc] = cb + (zc << 8) + (yc << 4) + xc;   // always a valid address
        int nc = min(cnt[cid[cc]], CAP);             // unconditional load
        n[cc] = ok ? nc : 0;
    }
    int nmax = 0;
#pragma unroll
    for (int cc = 0; cc < 4; cc++) nmax = max(nmax, n[cc]);

    for (int s = 0; s < nmax; s++) {
#pragma unroll
        for (int cc = 0; cc < 4; cc++) {
            if (s < n[cc]) {
                float4 q = bucket[cid[cc] * CAP + s];
                double ddx = xd - (double)q.x, ddy = yd - (double)q.y,
                       ddz = zd - (double)q.z;
                double d2 = ddx * ddx + ddy * ddy + ddz * ddz;
                if (d2 <= R2D) {
                    int slot = atomicAdd(&s_k[p], 1);
                    if (slot < NBR_STRIDE) {
                        s_hits[slot][p] = q;
                        nbr[i * NBR_STRIDE + slot] = q;
                    }
                }
            }
        }
    }
    __syncthreads();

    if (g == 0) {
        int kc = min(s_k[p], NBR_STRIDE);
        nbr_cnt[i] = kc;

        float mx[8];
#pragma unroll
        for (int m = 0; m < 8; m++) mx[m] = 0.f;   // self always valid, relu >= 0
        for (int kk = 0; kk < kc; kk++) {
            float4 q = s_hits[kk][p];
            float in6[6] = { q.x, q.y, q.z, q.x - xi, q.y - yi, q.z - zi };
#pragma unroll
            for (int m = 0; m < 8; m++) {
                float h = sB1[m];
#pragma unroll
                for (int c6 = 0; c6 < 6; c6++) h = fmaf(in6[c6], sW1[c6 * 8 + m], h);
                mx[m] = fmaxf(mx[m], fmaxf(h, 0.f));
            }
        }

        float o[8];
#pragma unroll
        for (int m = 0; m < 8; m++) {
            float v = sB2[m];
#pragma unroll
            for (int kk = 0; kk < 8; kk++) v = fmaf(mx[kk], sW2[kk * 8 + m], v);
            o[m] = v > 0.f ? v : expm1f(v);        // celu, alpha=1
        }
        *(float4*)&out_a[i * 8]     = make_float4(o[0], o[1], o[2], o[3]);
        *(float4*)&out_a[i * 8 + 4] = make_float4(o[4], o[5], o[6], o[7]);
    }
}

// ---------------------------------------------------------------------------
// K3/K4: PointNetConv, LDS-staged. Phase 1: threads (p, slot) gather the
// neighbor record + feature vectors into LDS IN PARALLEL (one 2-hop latency,
// ~CMID x fewer scattered lane-transactions than the per-channel version).
// Phase 2: threads (p, m) compute from LDS (same-address broadcast reads).
// FMA order per (p,m) identical to before -> bit-identical outputs.
// ---------------------------------------------------------------------------
template<int CIN4, int CMID, int PTS>
__global__ __launch_bounds__(256) void k_conv(
    const float4* __restrict__ pos4, const float4* __restrict__ xin4,
    const float4* __restrict__ nbr, const int* __restrict__ nbr_cnt,
    const float* __restrict__ W1, const float* __restrict__ b1,
    const float* __restrict__ W2, const float* __restrict__ b2,
    float* __restrict__ xout)
{
    constexpr int CIN = CIN4 * 4;
    __shared__ float4 s_q[PTS][NBR_STRIDE];           // neighbor pos+id
    __shared__ float4 s_x[PTS][NBR_STRIDE][CIN4];     // gathered features
    __shared__ float  s_agg[PTS][CMID + 1];           // +1 pad

    int tid = threadIdx.x;

    // ---- phase 1: parallel gather into LDS ----
#pragma unroll
    for (int w = tid; w < PTS * NBR_STRIDE; w += 256) {
        int sp = w >> 5, slot = w & 31;
        int si = blockIdx.x * PTS + sp;
        if (slot < nbr_cnt[si]) {
            float4 q = nbr[si * NBR_STRIDE + slot];
            s_q[sp][slot] = q;
            int j = __float_as_int(q.w);
#pragma unroll
            for (int k = 0; k < CIN4; k++) s_x[sp][slot][k] = xin4[j * CIN4 + k];
        }
    }
    __syncthreads();

    // ---- phase 2: per-(point, channel) compute from LDS ----
    int p = tid / CMID;
    int m = tid % CMID;
    int i = blockIdx.x * PTS + p;

    float4 pi = pos4[i];
    int cnt = nbr_cnt[i];

    float w1c[CIN + 3];
#pragma unroll
    for (int k = 0; k < CIN + 3; k++) w1c[k] = W1[k * CMID + m];
    float w2c[CMID];
#pragma unroll
    for (int k = 0; k < CMID; k++) w2c[k] = W2[k * CMID + m];
    float bb = b1[m];

    float mxv = 0.f;                                  // self always valid, relu >= 0
    for (int t = 0; t < cnt; t++) {
        float4 q = s_q[p][t];
        float h = bb;
#pragma unroll
        for (int k = 0; k < CIN4; k++) {
            float4 v = s_x[p][t][k];
            h = fmaf(v.x, w1c[4 * k],     h);
            h = fmaf(v.y, w1c[4 * k + 1], h);
            h = fmaf(v.z, w1c[4 * k + 2], h);
            h = fmaf(v.w, w1c[4 * k + 3], h);
        }
        h = fmaf(q.x - pi.x, w1c[CIN],     h);
        h = fmaf(q.y - pi.y, w1c[CIN + 1], h);
        h = fmaf(q.z - pi.z, w1c[CIN + 2], h);
        mxv = fmaxf(mxv, fmaxf(h, 0.f));
    }
    s_agg[p][m] = mxv;
    __syncthreads();

    float o = b2[m];
#pragma unroll
    for (int k = 0; k < CMID; k++) o = fmaf(s_agg[p][k], w2c[k], o);
    xout[i * CMID + m] = o > 0.f ? o : expm1f(o);     // celu, alpha=1
}

// ---------------------------------------------------------------------------
extern "C" void kernel_launch(void* const* d_in, const int* in_sizes, int n_in,
                              void* d_out, int out_size, void* d_ws, size_t ws_size,
                              hipStream_t stream)
{
    const float* pos   = (const float*)d_in[0];
    // d_in[1] = rgb: unused by reference
    const int*   batch = (const int*)d_in[2];
    const float* W1a = (const float*)d_in[3];
    const float* b1a = (const float*)d_in[4];
    const float* W2a = (const float*)d_in[5];
    const float* b2a = (const float*)d_in[6];
    const float* W1b = (const float*)d_in[7];
    const float* b1b = (const float*)d_in[8];
    const float* W2b = (const float*)d_in[9];
    const float* b2b = (const float*)d_in[10];
    const float* W1c = (const float*)d_in[11];
    const float* b1c = (const float*)d_in[12];
    const float* W2c = (const float*)d_in[13];
    const float* b2c = (const float*)d_in[14];

    float* out = (float*)d_out;

    char* ws = (char*)d_ws;
    size_t off = 0;
    auto alloc = [&](size_t bytes) {
        char* p = ws + off; off += (bytes + 255) & ~size_t(255); return p;
    };
    int*    cnt     = (int*)alloc(N_CELLS * 4);
    float4* bucket  = (float4*)alloc((size_t)N_CELLS * CAP * 16);
    float4* pos4    = (float4*)alloc(N_POINTS * 16);
    int*    nbr_cnt = (int*)alloc(N_POINTS * 4);
    float4* nbr     = (float4*)alloc((size_t)N_POINTS * NBR_STRIDE * 16);
    float*  out_a   = (float*)alloc(N_POINTS * 8 * 4);
    float*  out_b   = (float*)alloc(N_POINTS * 16 * 4);

    hipMemsetAsync(cnt, 0, N_CELLS * 4, stream);
    hipLaunchKernelGGL(k_prep, dim3(N_POINTS / 256), dim3(256), 0, stream,
                       pos, batch, out, cnt, bucket, pos4);
    hipLaunchKernelGGL(k_search_a, dim3(N_POINTS / 64), dim3(512), 0, stream,
                       pos4, cnt, bucket, W1a, b1a, W2a, b2a,
                       out_a, nbr, nbr_cnt);
    hipLaunchKernelGGL((k_conv<2, 16, 16>), dim3(N_POINTS / 16), dim3(256), 0, stream,
                       pos4, (const float4*)out_a, nbr, nbr_cnt,
                       W1b, b1b, W2b, b2b, out_b);
    hipLaunchKernelGGL((k_conv<4, 32, 8>), dim3(N_POINTS / 8), dim3(256), 0, stream,
                       pos4, (const float4*)out_b, nbr, nbr_cnt,
                       W1c, b1c, W2c, b2c, out + 3 * N_POINTS);
}

// Round 4
// 110.133 us; speedup vs baseline: 2.1990x; 1.0217x over previous
//
#include <hip/hip_runtime.h>
#include <math.h>

#define N_POINTS 16384
#define CELLS_PER_CLOUD 4096        // 16^3 per cloud, cell edge = r = 1/16
#define N_CELLS 32768               // 8 clouds
#define CAP 16                      // bucket capacity; lambda~0.5/cell, P(>16)~1e-12
#define NBR_STRIDE 32               // max neighbor count (established: cnt<=32)

constexpr double R2D = 1.0 / 256.0; // (1/16)^2, exact in binary

// Cell-occupancy counters live in .bss (zero-init at module load), NOT in the
// workspace: the harness re-poisons ws every iteration, so a ws-resident cnt
// would need a memset dispatch. Instead k_conv_c re-zeros g_cnt after the
// last read (k_search_a), restoring the all-zeros invariant for the next
// iteration's k_prep. This removes the hipMemsetAsync node entirely.
__device__ int g_cnt[N_CELLS];

// ---------------------------------------------------------------------------
// K1: output copies (pos, batch->float) + cell-bucket build + pos4 pack.
// 64 blocks x 256 = N_POINTS threads.
// ---------------------------------------------------------------------------
__global__ __launch_bounds__(256) void k_prep(const float* __restrict__ pos,
                                              const int* __restrict__ batch,
                                              float* __restrict__ out,
                                              float4* __restrict__ bucket,
                                              float4* __restrict__ pos4)
{
    int i = blockIdx.x * 256 + threadIdx.x;
    out[i]                = pos[i];                      // output 0: pos copy [N,3]
    out[i + N_POINTS]     = pos[i + N_POINTS];
    out[i + 2 * N_POINTS] = pos[i + 2 * N_POINTS];
    out[3 * N_POINTS + 32 * N_POINTS + i] = (float)batch[i];   // output 2

    float x = pos[3 * i], y = pos[3 * i + 1], z = pos[3 * i + 2];
    int ix = min(max((int)(x * 16.f), 0), 15);
    int iy = min(max((int)(y * 16.f), 0), 15);
    int iz = min(max((int)(z * 16.f), 0), 15);
    int cell = ((batch[i] * 16 + iz) * 16 + iy) * 16 + ix;
    pos4[i] = make_float4(x, y, z, __int_as_float(cell));
    int slot = atomicAdd(&g_cnt[cell], 1);
    if (slot < CAP) bucket[cell * CAP + slot] = make_float4(x, y, z, __int_as_float(i));
}

// ---------------------------------------------------------------------------
// K2: 27-cell radius search (fp64 test) fused with layer a (6->8->8).
// 16 threads per point (cells interleaved c = g + 16*cc), block = 512 threads
// = 32 points x 16 groups; 512 blocks -> 16 waves/CU (was 8). Per-thread
// serial candidate chain halves vs the 8-thread version. Hits compact via an
// LDS atomic slot counter; max-agg commutative -> order nondeterminism benign.
// Layer-a tail: 8 channel-threads per point (g<8), bit-identical FMA order.
// ---------------------------------------------------------------------------
__global__ __launch_bounds__(512) void k_search_a(
    const float4* __restrict__ pos4, const float4* __restrict__ bucket,
    const float* __restrict__ W1, const float* __restrict__ b1,
    const float* __restrict__ W2, const float* __restrict__ b2,
    float* __restrict__ out_a, float4* __restrict__ nbr, int* __restrict__ nbr_cnt)
{
    __shared__ float sW1[48], sB1[8], sW2[64], sB2[8];
    __shared__ float4 s_hits[NBR_STRIDE][32];   // [slot][point] : 16 KB
    __shared__ int   s_k[32];
    __shared__ float s_mx[32][9];               // +1 pad

    int t = threadIdx.x;
    int p = t & 31;          // point-in-block
    int g = t >> 5;          // cell-group 0..15

    if (t < 48) sW1[t] = W1[t];
    if (t < 8) { sB1[t] = b1[t]; sB2[t] = b2[t]; }
    if (t < 64) sW2[t] = W2[t];
    if (t < 32) s_k[t] = 0;
    __syncthreads();

    int i = blockIdx.x * 32 + p;
    float4 pi4 = pos4[i];
    float xi = pi4.x, yi = pi4.y, zi = pi4.z;
    double xd = (double)xi, yd = (double)yi, zd = (double)zi;
    int cell0 = __float_as_int(pi4.w);
    int ix = cell0 & 15, iy = (cell0 >> 4) & 15, iz = (cell0 >> 8) & 15;
    int cb = cell0 & ~(CELLS_PER_CLOUD - 1);

    // --- this thread's <=2 cells: counts, independent loads ---
    int n[2], cid[2];
#pragma unroll
    for (int cc = 0; cc < 2; cc++) {
        int c = g + 16 * cc;                      // 0..31; >=27 masked off
        int dz = c / 9 - 1, dy = (c / 3) % 3 - 1, dx = c % 3 - 1;
        int zz = iz + dz, yy = iy + dy, xx = ix + dx;
        bool ok = (c < 27) & ((zz | yy | xx) >= 0) & (zz < 16) & (yy < 16) & (xx < 16);
        int zc = min(max(zz, 0), 15), yc = min(max(yy, 0), 15),
            xc = min(max(xx, 0), 15);
        cid[cc] = cb + (zc << 8) + (yc << 4) + xc;   // always a valid address
        int nc = min(g_cnt[cid[cc]], CAP);           // unconditional load
        n[cc] = ok ? nc : 0;
    }
    int nmax = max(n[0], n[1]);

    // --- candidate rounds: load + fp64 test + LDS compact + global nbr store ---
    for (int s = 0; s < nmax; s++) {
#pragma unroll
        for (int cc = 0; cc < 2; cc++) {
            if (s < n[cc]) {
                float4 q = bucket[cid[cc] * CAP + s];
                double ddx = xd - (double)q.x, ddy = yd - (double)q.y,
                       ddz = zd - (double)q.z;
                double d2 = ddx * ddx + ddy * ddy + ddz * ddz;
                if (d2 <= R2D) {
                    int slot = atomicAdd(&s_k[p], 1);
                    if (slot < NBR_STRIDE) {
                        s_hits[slot][p] = q;
                        nbr[i * NBR_STRIDE + slot] = q;
                    }
                }
            }
        }
    }
    __syncthreads();
    int kc = min(s_k[p], NBR_STRIDE);

    if (g == 0) nbr_cnt[i] = kc;

    // --- layer-a: channel m = g, for g < 8 ---
    if (g < 8) {
        float mxv = 0.f;                            // self always valid, relu >= 0
        for (int kk = 0; kk < kc; kk++) {
            float4 q = s_hits[kk][p];
            float in6[6] = { q.x, q.y, q.z, q.x - xi, q.y - yi, q.z - zi };
            float h = sB1[g];
#pragma unroll
            for (int c6 = 0; c6 < 6; c6++) h = fmaf(in6[c6], sW1[c6 * 8 + g], h);
            mxv = fmaxf(mxv, fmaxf(h, 0.f));
        }
        s_mx[p][g] = mxv;
    }
    __syncthreads();
    if (g < 8) {
        float o = sB2[g];
#pragma unroll
        for (int k = 0; k < 8; k++) o = fmaf(s_mx[p][k], sW2[k * 8 + g], o);
        out_a[i * 8 + g] = o > 0.f ? o : expm1f(o);   // celu, alpha=1
    }
}

// ---------------------------------------------------------------------------
// K3/K4: PointNetConv, LDS-staged gather then per-(point,channel) compute.
// ZERO_CNT (conv_c only): re-zero g_cnt for the next iteration — runs after
// k_search_a's last read; visibility to next dispatch guaranteed at kernel end.
// ---------------------------------------------------------------------------
template<int CIN4, int CMID, int PTS, bool ZERO_CNT>
__global__ __launch_bounds__(256) void k_conv(
    const float4* __restrict__ pos4, const float4* __restrict__ xin4,
    const float4* __restrict__ nbr, const int* __restrict__ nbr_cnt,
    const float* __restrict__ W1, const float* __restrict__ b1,
    const float* __restrict__ W2, const float* __restrict__ b2,
    float* __restrict__ xout)
{
    constexpr int CIN = CIN4 * 4;
    __shared__ float4 s_q[PTS][NBR_STRIDE];           // neighbor pos+id
    __shared__ float4 s_x[PTS][NBR_STRIDE][CIN4];     // gathered features
    __shared__ float  s_agg[PTS][CMID + 1];           // +1 pad

    int tid = threadIdx.x;

    if (ZERO_CNT) {
        int gid = blockIdx.x * 256 + tid;
        if (gid < N_CELLS) g_cnt[gid] = 0;
    }

    // ---- phase 1: parallel gather into LDS ----
#pragma unroll
    for (int w = tid; w < PTS * NBR_STRIDE; w += 256) {
        int sp = w >> 5, slot = w & 31;
        int si = blockIdx.x * PTS + sp;
        if (slot < nbr_cnt[si]) {
            float4 q = nbr[si * NBR_STRIDE + slot];
            s_q[sp][slot] = q;
            int j = __float_as_int(q.w);
#pragma unroll
            for (int k = 0; k < CIN4; k++) s_x[sp][slot][k] = xin4[j * CIN4 + k];
        }
    }
    __syncthreads();

    // ---- phase 2: per-(point, channel) compute from LDS ----
    int p = tid / CMID;
    int m = tid % CMID;
    int i = blockIdx.x * PTS + p;

    float4 pi = pos4[i];
    int cnt = nbr_cnt[i];

    float w1c[CIN + 3];
#pragma unroll
    for (int k = 0; k < CIN + 3; k++) w1c[k] = W1[k * CMID + m];
    float w2c[CMID];
#pragma unroll
    for (int k = 0; k < CMID; k++) w2c[k] = W2[k * CMID + m];
    float bb = b1[m];

    float mxv = 0.f;                                  // self always valid, relu >= 0
    for (int t = 0; t < cnt; t++) {
        float4 q = s_q[p][t];
        float h = bb;
#pragma unroll
        for (int k = 0; k < CIN4; k++) {
            float4 v = s_x[p][t][k];
            h = fmaf(v.x, w1c[4 * k],     h);
            h = fmaf(v.y, w1c[4 * k + 1], h);
            h = fmaf(v.z, w1c[4 * k + 2], h);
            h = fmaf(v.w, w1c[4 * k + 3], h);
        }
        h = fmaf(q.x - pi.x, w1c[CIN],     h);
        h = fmaf(q.y - pi.y, w1c[CIN + 1], h);
        h = fmaf(q.z - pi.z, w1c[CIN + 2], h);
        mxv = fmaxf(mxv, fmaxf(h, 0.f));
    }
    s_agg[p][m] = mxv;
    __syncthreads();

    float o = b2[m];
#pragma unroll
    for (int k = 0; k < CMID; k++) o = fmaf(s_agg[p][k], w2c[k], o);
    xout[i * CMID + m] = o > 0.f ? o : expm1f(o);     // celu, alpha=1
}

// ---------------------------------------------------------------------------
extern "C" void kernel_launch(void* const* d_in, const int* in_sizes, int n_in,
                              void* d_out, int out_size, void* d_ws, size_t ws_size,
                              hipStream_t stream)
{
    const float* pos   = (const float*)d_in[0];
    // d_in[1] = rgb: unused by reference
    const int*   batch = (const int*)d_in[2];
    const float* W1a = (const float*)d_in[3];
    const float* b1a = (const float*)d_in[4];
    const float* W2a = (const float*)d_in[5];
    const float* b2a = (const float*)d_in[6];
    const float* W1b = (const float*)d_in[7];
    const float* b1b = (const float*)d_in[8];
    const float* W2b = (const float*)d_in[9];
    const float* b2b = (const float*)d_in[10];
    const float* W1c = (const float*)d_in[11];
    const float* b1c = (const float*)d_in[12];
    const float* W2c = (const float*)d_in[13];
    const float* b2c = (const float*)d_in[14];

    float* out = (float*)d_out;

    char* ws = (char*)d_ws;
    size_t off = 0;
    auto alloc = [&](size_t bytes) {
        char* p = ws + off; off += (bytes + 255) & ~size_t(255); return p;
    };
    float4* bucket  = (float4*)alloc((size_t)N_CELLS * CAP * 16);
    float4* pos4    = (float4*)alloc(N_POINTS * 16);
    int*    nbr_cnt = (int*)alloc(N_POINTS * 4);
    float4* nbr     = (float4*)alloc((size_t)N_POINTS * NBR_STRIDE * 16);
    float*  out_a   = (float*)alloc(N_POINTS * 8 * 4);
    float*  out_b   = (float*)alloc(N_POINTS * 16 * 4);

    hipLaunchKernelGGL(k_prep, dim3(N_POINTS / 256), dim3(256), 0, stream,
                       pos, batch, out, bucket, pos4);
    hipLaunchKernelGGL(k_search_a, dim3(N_POINTS / 32), dim3(512), 0, stream,
                       pos4, bucket, W1a, b1a, W2a, b2a,
                       out_a, nbr, nbr_cnt);
    hipLaunchKernelGGL((k_conv<2, 16, 16, false>), dim3(N_POINTS / 16), dim3(256), 0, stream,
                       pos4, (const float4*)out_a, nbr, nbr_cnt,
                       W1b, b1b, W2b, b2b, out_b);
    hipLaunchKernelGGL((k_conv<4, 32, 8, true>), dim3(N_POINTS / 8), dim3(256), 0, stream,
                       pos4, (const float4*)out_b, nbr, nbr_cnt,
                       W1c, b1c, W2c, b2c, out + 3 * N_POINTS);
}